// Round 6
// baseline (1109.644 us; speedup 1.0000x reference)
//
#include <hip/hip_runtime.h>
#include <stdint.h>

#define EMB   768
#define HEADS 8
#define HDIM  96
#define SEQ   2048
#define BATCH 4
#define MROWS (BATCH*SEQ)     // 8192

typedef unsigned short ushort_t;
typedef __bf16 bf16x8 __attribute__((ext_vector_type(8)));
typedef float  fx4    __attribute__((ext_vector_type(4)));
typedef uint4  uint4_a  __attribute__((may_alias));
typedef uint2  uint2_a  __attribute__((may_alias));
typedef bf16x8 bf16x8_a __attribute__((may_alias));

__device__ __forceinline__ float bf2f(ushort_t u) {
    uint32_t v = ((uint32_t)u) << 16;
    return __builtin_bit_cast(float, v);
}
__device__ __forceinline__ ushort_t f2bf(float f) {
    uint32_t u = __builtin_bit_cast(uint32_t, f);
    u += 0x7fffu + ((u >> 16) & 1u);   // RNE
    return (ushort_t)(u >> 16);
}

// flag=1 -> input words are f32 (incl. bf16-rounded f32); flag=0 -> packed bf16
__global__ __launch_bounds__(256) void detect_f32(const uint32_t* __restrict__ x,
                                                  int* __restrict__ flag) {
    __shared__ int cnt;
    if (threadIdx.x == 0) cnt = 0;
    __syncthreads();
    int local = 0;
    for (int i = threadIdx.x; i < 4096; i += 256) {
        uint32_t e = (x[i] >> 7) & 0xFFu;
        local += (e >= 64u && e <= 143u) ? 1 : 0;
    }
    atomicAdd(&cnt, local);
    __syncthreads();
    if (threadIdx.x == 0) *flag = (cnt < 3500) ? 1 : 0;
}

// ---------------- QKV GEMM for one (b,h) unit slice ----------------
// grid (16, 3, gc). Unit u = u0+z: b=u>>3, h=u&7. x[b rows] @ Wqkv[:, h*288..+288)
// -> stage[g]: Q[2048][96], K[2048][96], Vt[96][2048] (bf16).
__global__ __launch_bounds__(256, 2) void qkv_mfma(
        const void* __restrict__ x, const void* __restrict__ W, const void* __restrict__ bias,
        ushort_t* __restrict__ stage, int u0, const int* __restrict__ flag)
{
    __shared__ __attribute__((aligned(16))) ushort_t lA[128 * 32];
    __shared__ __attribute__((aligned(16))) ushort_t lB[96 * 32];
    const int g = blockIdx.z, u = u0 + g;
    const int b = u >> 3, h = u & 7;
    const int m0 = blockIdx.x * 128;          // row within batch b
    const int n0 = blockIdx.y * 96;           // col within head slice [0,288)
    const bool isf = (*flag != 0);
    const int t = threadIdx.x, lane = t & 63, wave = t >> 6;
    const int lx = lane & 15, quad = lane >> 4;
    const int wm = (wave & 1) * 64, wn = (wave >> 1) * 48;
    const int hb = h * 288;
    const size_t xrow0 = (size_t)(b * SEQ + m0) * EMB;

    ushort_t* Qg = stage + (size_t)g * (3 * SEQ * HDIM);
    ushort_t* Kg = Qg + SEQ * HDIM;
    ushort_t* Vg = Qg + 2 * SEQ * HDIM;

    fx4 acc[4][3] = {};

    for (int kt = 0; kt < EMB / 32; ++kt) {
        const int k0 = kt * 32;
        __syncthreads();
        if (isf) {
            const float* xf = (const float*)x;
#pragma unroll
            for (int it = 0; it < 4; ++it) {
                int idx = it * 256 + t;              // 1024 float4 segs
                int r = idx >> 3, k4 = (idx & 7) * 4;
                float4 v = *(const float4*)&xf[xrow0 + (size_t)r * EMB + k0 + k4];
                ushort_t tmp[4] = { f2bf(v.x), f2bf(v.y), f2bf(v.z), f2bf(v.w) };
                *(uint2_a*)&lA[r * 32 + k4] = *(const uint2_a*)tmp;
            }
        } else {
            const ushort_t* xb = (const ushort_t*)x;
#pragma unroll
            for (int it = 0; it < 2; ++it) {
                int idx = it * 256 + t;              // 512 8-elem segs
                int r = idx >> 2, k8 = (idx & 3) * 8;
                *(uint4_a*)&lA[r * 32 + k8] = *(const uint4_a*)&xb[xrow0 + (size_t)r * EMB + k0 + k8];
            }
        }
        // B tile transposed inline: lB[c*32+kk] = W[(k0+kk)*2304 + hb + n0 + c]
#pragma unroll
        for (int it = 0; it < 12; ++it) {
            int idx = it * 256 + t;                  // 3072 = 96c x 32k
            int kk = idx / 96, c = idx - kk * 96;
            size_t off = (size_t)(k0 + kk) * 2304 + hb + n0 + c;
            float w = isf ? ((const float*)W)[off] : bf2f(((const ushort_t*)W)[off]);
            lB[c * 32 + kk] = f2bf(w);
        }
        __syncthreads();

        bf16x8 af[4], bfr[3];
#pragma unroll
        for (int i = 0; i < 4; ++i)
            af[i] = *(const bf16x8_a*)&lA[(wm + i * 16 + lx) * 32 + quad * 8];
#pragma unroll
        for (int j = 0; j < 3; ++j)
            bfr[j] = *(const bf16x8_a*)&lB[(wn + j * 16 + lx) * 32 + quad * 8];
#pragma unroll
        for (int i = 0; i < 4; ++i)
#pragma unroll
            for (int j = 0; j < 3; ++j)
                acc[i][j] = __builtin_amdgcn_mfma_f32_16x16x32_bf16(af[i], bfr[j], acc[i][j], 0, 0, 0);
    }

    // epilogue: C/D col=lane&15, row=quad*4+reg.  c_local = d*3+s
#pragma unroll
    for (int j = 0; j < 3; ++j) {
        const int cl = n0 + wn + j * 16 + lx;        // [0,288)
        const int dd = cl / 3, s = cl - dd * 3;
        const float bv = isf ? ((const float*)bias)[hb + cl]
                             : bf2f(((const ushort_t*)bias)[hb + cl]);
#pragma unroll
        for (int i = 0; i < 4; ++i) {
            const int ml = m0 + wm + i * 16 + quad * 4;
#pragma unroll
            for (int r = 0; r < 4; ++r) {
                const int nseq = ml + r;
                const ushort_t val = f2bf(acc[i][j][r] + bv);
                if (s == 0)      Qg[(size_t)nseq * HDIM + dd] = val;
                else if (s == 1) Kg[(size_t)nseq * HDIM + dd] = val;
                else             Vg[(size_t)dd * SEQ + nseq] = val;
            }
        }
    }
}

// ---------------- flash attention, unit-local; O (bf16) -> Ob[b][n][h*96+d] ----------------
__global__ __launch_bounds__(256, 2) void attn_flash(
        const ushort_t* __restrict__ stage, ushort_t* __restrict__ O, int u0)
{
    __shared__ __attribute__((aligned(16))) ushort_t lQ[64 * 96];
    __shared__ __attribute__((aligned(16))) ushort_t lK[64 * 96];
    __shared__ __attribute__((aligned(16))) ushort_t lV[96 * 64];
    __shared__ __attribute__((aligned(16))) ushort_t lP[4][16 * 64];
    const int t = threadIdx.x, lane = t & 63, wave = t >> 6;
    const int lx = lane & 15, quad = lane >> 4;
    const int qt = blockIdx.x, g = blockIdx.y, u = u0 + g;
    const int b = u >> 3, h = u & 7;
    const ushort_t* Qb = stage + (size_t)g * (3 * SEQ * HDIM);
    const ushort_t* Kb = Qb + SEQ * HDIM;
    const ushort_t* Vb = Qb + 2 * SEQ * HDIM;
    const float scale = 0.03608439182435161f;   // 1/sqrt(768)

#pragma unroll
    for (int it = 0; it < 3; ++it) {
        int idx = it * 256 + t;               // 768 8-elem segs
        int r = idx / 12, s8 = (idx % 12) * 8;
        *(uint4_a*)&lQ[r * 96 + s8] = *(const uint4_a*)&Qb[(size_t)(qt * 64 + r) * HDIM + s8];
    }

    fx4 accO[6] = {};
    float mrow[4] = {-1e30f, -1e30f, -1e30f, -1e30f};
    float lrow[4] = {0.f, 0.f, 0.f, 0.f};

    for (int kt = 0; kt < SEQ / 64; ++kt) {
        __syncthreads();
#pragma unroll
        for (int it = 0; it < 3; ++it) {
            int idx = it * 256 + t;
            { int r = idx / 12, s8 = (idx % 12) * 8;
              *(uint4_a*)&lK[r * 96 + s8] = *(const uint4_a*)&Kb[(size_t)(kt * 64 + r) * HDIM + s8]; }
            { int r = idx >> 3, s8 = (idx & 7) * 8;
              *(uint4_a*)&lV[r * 64 + s8] = *(const uint4_a*)&Vb[(size_t)r * SEQ + kt * 64 + s8]; }
        }
        __syncthreads();

        fx4 accS[4] = {};
#pragma unroll
        for (int kd = 0; kd < 3; ++kd) {
            bf16x8 aq = *(const bf16x8_a*)&lQ[(wave * 16 + lx) * 96 + kd * 32 + quad * 8];
#pragma unroll
            for (int j = 0; j < 4; ++j) {
                bf16x8 bk = *(const bf16x8_a*)&lK[(j * 16 + lx) * 96 + kd * 32 + quad * 8];
                accS[j] = __builtin_amdgcn_mfma_f32_16x16x32_bf16(aq, bk, accS[j], 0, 0, 0);
            }
        }

#pragma unroll
        for (int r = 0; r < 4; ++r) {
            float mx = fmaxf(fmaxf(accS[0][r], accS[1][r]), fmaxf(accS[2][r], accS[3][r]));
#pragma unroll
            for (int off = 1; off < 16; off <<= 1) mx = fmaxf(mx, __shfl_xor(mx, off, 64));
            mx *= scale;
            const float mnew = fmaxf(mrow[r], mx);
            const float alpha = __expf(mrow[r] - mnew);
            float rsum = 0.f;
#pragma unroll
            for (int j = 0; j < 4; ++j) {
                float p = __expf(accS[j][r] * scale - mnew);
                rsum += p;
                lP[wave][(quad * 4 + r) * 64 + j * 16 + lx] = f2bf(p);
            }
#pragma unroll
            for (int off = 1; off < 16; off <<= 1) rsum += __shfl_xor(rsum, off, 64);
            lrow[r] = lrow[r] * alpha + rsum;
            mrow[r] = mnew;
#pragma unroll
            for (int d = 0; d < 6; ++d) accO[d][r] *= alpha;
        }
        __syncthreads();

#pragma unroll
        for (int kk = 0; kk < 2; ++kk) {
            bf16x8 ap = *(const bf16x8_a*)&lP[wave][lx * 64 + kk * 32 + quad * 8];
#pragma unroll
            for (int d = 0; d < 6; ++d) {
                bf16x8 bv = *(const bf16x8_a*)&lV[(d * 16 + lx) * 64 + kk * 32 + quad * 8];
                accO[d] = __builtin_amdgcn_mfma_f32_16x16x32_bf16(ap, bv, accO[d], 0, 0, 0);
            }
        }
    }

#pragma unroll
    for (int r = 0; r < 4; ++r) {
        const float inv = 1.0f / lrow[r];
        const int nseq = qt * 64 + wave * 16 + quad * 4 + r;
        ushort_t* orow = O + ((size_t)(b * SEQ + nseq)) * EMB + h * HDIM;
#pragma unroll
        for (int d = 0; d < 6; ++d)
            orow[d * 16 + lx] = f2bf(accO[d][r] * inv);
    }
}

// ---------------- projection: Ob (bf16) @ Wproj + bproj -> d_out (FLOAT32) ----------------
__global__ __launch_bounds__(256, 2) void proj_mfma(
        const ushort_t* __restrict__ O, float* __restrict__ out,
        const void* __restrict__ W, const void* __restrict__ bias,
        const int* __restrict__ flag)
{
    __shared__ __attribute__((aligned(16))) ushort_t lO[32 * 768];   // 48 KB
    __shared__ __attribute__((aligned(16))) ushort_t lB[128 * 32];   // 8 KB
    const int m0 = blockIdx.x * 32;
    const bool isf = (*flag != 0);
    const int t = threadIdx.x, lane = t & 63, wave = t >> 6;
    const int lx = lane & 15, quad = lane >> 4;

#pragma unroll
    for (int it = 0; it < 12; ++it) {
        int idx = it * 256 + t;                  // 3072 8-elem segs = 32x768
        int r = idx / 96, s8 = (idx % 96) * 8;
        *(uint4_a*)&lO[r * 768 + s8] = *(const uint4_a*)&O[(size_t)(m0 + r) * EMB + s8];
    }
    __syncthreads();

    for (int nb = 0; nb < 6; ++nb) {
        const int n0 = nb * 128;
        fx4 acc[2][2] = {};
        for (int kt = 0; kt < 24; ++kt) {
            __syncthreads();   // protect lB reuse
#pragma unroll
            for (int it = 0; it < 16; ++it) {
                int idx = it * 256 + t;          // 4096 = 128c x 32k
                int kk = idx >> 7, c = idx & 127;
                size_t off = (size_t)(kt * 32 + kk) * EMB + n0 + c;
                float w = isf ? ((const float*)W)[off] : bf2f(((const ushort_t*)W)[off]);
                lB[c * 32 + kk] = f2bf(w);
            }
            __syncthreads();
            bf16x8 af[2], bfr[2];
#pragma unroll
            for (int i = 0; i < 2; ++i)
                af[i] = *(const bf16x8_a*)&lO[(i * 16 + lx) * 768 + kt * 32 + quad * 8];
#pragma unroll
            for (int j = 0; j < 2; ++j)
                bfr[j] = *(const bf16x8_a*)&lB[(wave * 32 + j * 16 + lx) * 32 + quad * 8];
#pragma unroll
            for (int i = 0; i < 2; ++i)
#pragma unroll
                for (int j = 0; j < 2; ++j)
                    acc[i][j] = __builtin_amdgcn_mfma_f32_16x16x32_bf16(af[i], bfr[j], acc[i][j], 0, 0, 0);
        }
#pragma unroll
        for (int j = 0; j < 2; ++j) {
            const int c = n0 + wave * 32 + j * 16 + lx;
            const float bv = isf ? ((const float*)bias)[c] : bf2f(((const ushort_t*)bias)[c]);
#pragma unroll
            for (int i = 0; i < 2; ++i) {
                const int mr = m0 + i * 16 + quad * 4;
#pragma unroll
                for (int r = 0; r < 4; ++r)
                    out[(size_t)(mr + r) * EMB + c] = acc[i][j][r] + bv;   // f32 store
            }
        }
    }
}

// ---------------- launch ----------------
extern "C" void kernel_launch(void* const* d_in, const int* in_sizes, int n_in,
                              void* d_out, int out_size, void* d_ws, size_t ws_size,
                              hipStream_t stream) {
    const void* x     = d_in[0];
    const void* Wqkv  = d_in[1];
    const void* bqkv  = d_in[2];
    const void* Wproj = d_in[3];
    const void* bproj = d_in[4];
    float* out = (float*)d_out;     // OUTPUT IS FLOAT32 (reference dtype)

    char* ws = (char*)d_ws;
    int* flag = (int*)ws;
    ushort_t* Ob = (ushort_t*)(ws + 1024);                  // attention out, bf16, 12.58 MB
    const size_t OB_BYTES = (size_t)MROWS * EMB * 2;
    ushort_t* stage = (ushort_t*)(ws + 1024 + OB_BYTES);
    const size_t SLOT_BYTES = (size_t)3 * SEQ * HDIM * 2;   // 1.18 MB per (b,h) unit
    size_t used = 1024 + OB_BYTES;
    size_t avail = ws_size > used ? ws_size - used : 0;
    int G = (int)(avail / SLOT_BYTES);
    if (G < 1) G = 1;
    if (G > 32) G = 32;

    detect_f32<<<1, 256, 0, stream>>>((const uint32_t*)x, flag);
    for (int u0 = 0; u0 < 32; u0 += G) {
        const int gc = (32 - u0 < G) ? (32 - u0) : G;
        qkv_mfma<<<dim3(16, 3, gc), 256, 0, stream>>>(x, Wqkv, bqkv, stage, u0, flag);
        attn_flash<<<dim3(SEQ / 64, gc), 256, 0, stream>>>(stage, Ob, u0);
    }
    proj_mfma<<<dim3(MROWS / 32), 256, 0, stream>>>(Ob, out, Wproj, bproj, flag);
}

// Round 8
// 421.450 us; speedup vs baseline: 2.6329x; 2.6329x over previous
//
#include <hip/hip_runtime.h>
#include <stdint.h>

#define EMB   768
#define HEADS 8
#define HDIM  96
#define SEQ   2048
#define BATCH 4
#define MROWS (BATCH*SEQ)     // 8192

typedef unsigned short ushort_t;
typedef __bf16 bf16x8 __attribute__((ext_vector_type(8)));
typedef float  fx4    __attribute__((ext_vector_type(4)));
typedef uint4  uint4_a  __attribute__((may_alias));
typedef uint2  uint2_a  __attribute__((may_alias));
typedef bf16x8 bf16x8_a __attribute__((may_alias));

__device__ __forceinline__ float bf2f(ushort_t u) {
    uint32_t v = ((uint32_t)u) << 16;
    return __builtin_bit_cast(float, v);
}
__device__ __forceinline__ ushort_t f2bf(float f) {
    uint32_t u = __builtin_bit_cast(uint32_t, f);
    u += 0x7fffu + ((u >> 16) & 1u);   // RNE
    return (ushort_t)(u >> 16);
}

// flag=1 -> input words are f32; flag=0 -> packed bf16 (kept for robustness)
__global__ __launch_bounds__(256) void detect_f32(const uint32_t* __restrict__ x,
                                                  int* __restrict__ flag) {
    __shared__ int cnt;
    if (threadIdx.x == 0) cnt = 0;
    __syncthreads();
    int local = 0;
    for (int i = threadIdx.x; i < 4096; i += 256) {
        uint32_t e = (x[i] >> 7) & 0xFFu;
        local += (e >= 64u && e <= 143u) ? 1 : 0;
    }
    atomicAdd(&cnt, local);
    __syncthreads();
    if (threadIdx.x == 0) *flag = (cnt < 3500) ? 1 : 0;
}

// ---------------- weight transpose (+f32->bf16): src[R][C] -> dst[C][R] bf16 ----------------
__global__ __launch_bounds__(256) void transpose_conv(
        const void* __restrict__ vsrc, ushort_t* __restrict__ dst,
        int R, int C, const int* __restrict__ flag)
{
    __shared__ __attribute__((aligned(16))) ushort_t tile[64][72];  // +8 pad
    const int c0 = blockIdx.x * 64, r0 = blockIdx.y * 64;
    const int t = threadIdx.x;
    const int isf32 = *flag;
#pragma unroll
    for (int i = 0; i < 2; ++i) {
        int idx = i * 256 + t;           // 512 x 8-elem segments
        int r = idx >> 3, c8 = (idx & 7) * 8;
        if (isf32) {
            const float* s = (const float*)vsrc + (size_t)(r0 + r) * C + c0 + c8;
            float4 v0 = *(const float4*)s, v1 = *(const float4*)(s + 4);
            ushort_t tmp[8] = { f2bf(v0.x), f2bf(v0.y), f2bf(v0.z), f2bf(v0.w),
                                f2bf(v1.x), f2bf(v1.y), f2bf(v1.z), f2bf(v1.w) };
            *(uint4_a*)&tile[r][c8] = *(const uint4_a*)tmp;
        } else {
            const ushort_t* s = (const ushort_t*)vsrc + (size_t)(r0 + r) * C + c0 + c8;
            *(uint4_a*)&tile[r][c8] = *(const uint4_a*)s;
        }
    }
    __syncthreads();
#pragma unroll
    for (int i = 0; i < 2; ++i) {
        int idx = i * 256 + t;
        int r = idx >> 3, k8 = (idx & 7) * 8;
        ushort_t tmp[8];
#pragma unroll
        for (int j = 0; j < 8; ++j) tmp[j] = tile[k8 + j][r];
        *(uint4_a*)&dst[(size_t)(c0 + r) * R + r0 + k8] = *(const uint4_a*)tmp;
    }
}

// ---------------- QKV GEMM for one (b,h) unit slice ----------------
// grid (16, 3, gc). Unit u=u0+z: b=u>>3, h=u&7. x[b rows] @ Wqkv[:, h*288..+288)
// Wt1: pre-transposed bf16 [2304][768]. -> stage[g]: Q[2048][96],K[2048][96],Vt[96][2048]
__global__ __launch_bounds__(256, 2) void qkv_mfma(
        const void* __restrict__ x, const ushort_t* __restrict__ Wt1,
        const void* __restrict__ bias,
        ushort_t* __restrict__ stage, int u0, const int* __restrict__ flag)
{
    __shared__ __attribute__((aligned(16))) ushort_t lA[128 * 32];
    __shared__ __attribute__((aligned(16))) ushort_t lB[96 * 32];
    const int g = blockIdx.z, u = u0 + g;
    const int b = u >> 3, h = u & 7;
    const int m0 = blockIdx.x * 128;
    const int n0 = blockIdx.y * 96;           // col within head slice [0,288)
    const bool isf = (*flag != 0);
    const int t = threadIdx.x, lane = t & 63, wave = t >> 6;
    const int lx = lane & 15, quad = lane >> 4;
    const int wm = (wave & 1) * 64, wn = (wave >> 1) * 48;
    const int hb = h * 288;
    const size_t xrow0 = (size_t)(b * SEQ + m0) * EMB;

    ushort_t* Qg = stage + (size_t)g * (3 * SEQ * HDIM);
    ushort_t* Kg = Qg + SEQ * HDIM;
    ushort_t* Vg = Qg + 2 * SEQ * HDIM;

    fx4 acc[4][3] = {};

    for (int kt = 0; kt < EMB / 32; ++kt) {
        const int k0 = kt * 32;
        __syncthreads();
        if (isf) {
            const float* xf = (const float*)x;
#pragma unroll
            for (int it = 0; it < 4; ++it) {
                int idx = it * 256 + t;              // 1024 float4 segs
                int r = idx >> 3, k4 = (idx & 7) * 4;
                float4 v = *(const float4*)&xf[xrow0 + (size_t)r * EMB + k0 + k4];
                ushort_t tmp[4] = { f2bf(v.x), f2bf(v.y), f2bf(v.z), f2bf(v.w) };
                *(uint2_a*)&lA[r * 32 + k4] = *(const uint2_a*)tmp;
            }
        } else {
            const ushort_t* xb = (const ushort_t*)x;
#pragma unroll
            for (int it = 0; it < 2; ++it) {
                int idx = it * 256 + t;
                int r = idx >> 2, k8 = (idx & 3) * 8;
                *(uint4_a*)&lA[r * 32 + k8] = *(const uint4_a*)&xb[xrow0 + (size_t)r * EMB + k0 + k8];
            }
        }
        // B tile from Wt1: 384 segs = 96 rows x 4 segs; thread t does seg t,
        // and threads t<128 also do seg 256+t.  (Round-7 bug: segs 0..127 were skipped.)
        {
            int c = t >> 2, s8 = (t & 3) * 8;
            *(uint4_a*)&lB[c * 32 + s8] =
                *(const uint4_a*)&Wt1[(size_t)(hb + n0 + c) * EMB + k0 + s8];
            if (t < 128) {
                int idx = 256 + t;
                int c2 = idx >> 2, s82 = (idx & 3) * 8;
                *(uint4_a*)&lB[c2 * 32 + s82] =
                    *(const uint4_a*)&Wt1[(size_t)(hb + n0 + c2) * EMB + k0 + s82];
            }
        }
        __syncthreads();

        bf16x8 af[4], bfr[3];
#pragma unroll
        for (int i = 0; i < 4; ++i)
            af[i] = *(const bf16x8_a*)&lA[(wm + i * 16 + lx) * 32 + quad * 8];
#pragma unroll
        for (int j = 0; j < 3; ++j)
            bfr[j] = *(const bf16x8_a*)&lB[(wn + j * 16 + lx) * 32 + quad * 8];
#pragma unroll
        for (int i = 0; i < 4; ++i)
#pragma unroll
            for (int j = 0; j < 3; ++j)
                acc[i][j] = __builtin_amdgcn_mfma_f32_16x16x32_bf16(af[i], bfr[j], acc[i][j], 0, 0, 0);
    }

    // epilogue: C/D col=lane&15, row=quad*4+reg.  c_local = d*3+s
#pragma unroll
    for (int j = 0; j < 3; ++j) {
        const int cl = n0 + wn + j * 16 + lx;        // [0,288)
        const int dd = cl / 3, s = cl - dd * 3;
        const float bv = isf ? ((const float*)bias)[hb + cl]
                             : bf2f(((const ushort_t*)bias)[hb + cl]);
#pragma unroll
        for (int i = 0; i < 4; ++i) {
            const int ml = m0 + wm + i * 16 + quad * 4;
#pragma unroll
            for (int r = 0; r < 4; ++r) {
                const int nseq = ml + r;
                const ushort_t val = f2bf(acc[i][j][r] + bv);
                if (s == 0)      Qg[(size_t)nseq * HDIM + dd] = val;
                else if (s == 1) Kg[(size_t)nseq * HDIM + dd] = val;
                else             Vg[(size_t)dd * SEQ + nseq] = val;
            }
        }
    }
}

// ---------------- flash attention, unit-local; O (bf16) -> Ob[b][n][h*96+d] ----------------
__global__ __launch_bounds__(256, 2) void attn_flash(
        const ushort_t* __restrict__ stage, ushort_t* __restrict__ O, int u0)
{
    __shared__ __attribute__((aligned(16))) ushort_t lQ[64 * 96];
    __shared__ __attribute__((aligned(16))) ushort_t lK[64 * 96];
    __shared__ __attribute__((aligned(16))) ushort_t lV[96 * 64];
    __shared__ __attribute__((aligned(16))) ushort_t lP[4][16 * 64];
    const int t = threadIdx.x, lane = t & 63, wave = t >> 6;
    const int lx = lane & 15, quad = lane >> 4;
    const int qt = blockIdx.x, g = blockIdx.y, u = u0 + g;
    const int b = u >> 3, h = u & 7;
    const ushort_t* Qb = stage + (size_t)g * (3 * SEQ * HDIM);
    const ushort_t* Kb = Qb + SEQ * HDIM;
    const ushort_t* Vb = Qb + 2 * SEQ * HDIM;
    const float scale = 0.03608439182435161f;   // 1/sqrt(768)

#pragma unroll
    for (int it = 0; it < 3; ++it) {
        int idx = it * 256 + t;
        int r = idx / 12, s8 = (idx % 12) * 8;
        *(uint4_a*)&lQ[r * 96 + s8] = *(const uint4_a*)&Qb[(size_t)(qt * 64 + r) * HDIM + s8];
    }

    fx4 accO[6] = {};
    float mrow[4] = {-1e30f, -1e30f, -1e30f, -1e30f};
    float lrow[4] = {0.f, 0.f, 0.f, 0.f};

    for (int kt = 0; kt < SEQ / 64; ++kt) {
        __syncthreads();
#pragma unroll
        for (int it = 0; it < 3; ++it) {
            int idx = it * 256 + t;
            { int r = idx / 12, s8 = (idx % 12) * 8;
              *(uint4_a*)&lK[r * 96 + s8] = *(const uint4_a*)&Kb[(size_t)(kt * 64 + r) * HDIM + s8]; }
            { int r = idx >> 3, s8 = (idx & 7) * 8;
              *(uint4_a*)&lV[r * 64 + s8] = *(const uint4_a*)&Vb[(size_t)r * SEQ + kt * 64 + s8]; }
        }
        __syncthreads();

        fx4 accS[4] = {};
#pragma unroll
        for (int kd = 0; kd < 3; ++kd) {
            bf16x8 aq = *(const bf16x8_a*)&lQ[(wave * 16 + lx) * 96 + kd * 32 + quad * 8];
#pragma unroll
            for (int j = 0; j < 4; ++j) {
                bf16x8 bk = *(const bf16x8_a*)&lK[(j * 16 + lx) * 96 + kd * 32 + quad * 8];
                accS[j] = __builtin_amdgcn_mfma_f32_16x16x32_bf16(aq, bk, accS[j], 0, 0, 0);
            }
        }

#pragma unroll
        for (int r = 0; r < 4; ++r) {
            float mx = fmaxf(fmaxf(accS[0][r], accS[1][r]), fmaxf(accS[2][r], accS[3][r]));
#pragma unroll
            for (int off = 1; off < 16; off <<= 1) mx = fmaxf(mx, __shfl_xor(mx, off, 64));
            mx *= scale;
            const float mnew = fmaxf(mrow[r], mx);
            const float alpha = __expf(mrow[r] - mnew);
            float rsum = 0.f;
#pragma unroll
            for (int j = 0; j < 4; ++j) {
                float p = __expf(accS[j][r] * scale - mnew);
                rsum += p;
                lP[wave][(quad * 4 + r) * 64 + j * 16 + lx] = f2bf(p);
            }
#pragma unroll
            for (int off = 1; off < 16; off <<= 1) rsum += __shfl_xor(rsum, off, 64);
            lrow[r] = lrow[r] * alpha + rsum;
            mrow[r] = mnew;
#pragma unroll
            for (int d = 0; d < 6; ++d) accO[d][r] *= alpha;
        }
        __syncthreads();

#pragma unroll
        for (int kk = 0; kk < 2; ++kk) {
            bf16x8 ap = *(const bf16x8_a*)&lP[wave][lx * 64 + kk * 32 + quad * 8];
#pragma unroll
            for (int d = 0; d < 6; ++d) {
                bf16x8 bv = *(const bf16x8_a*)&lV[(d * 16 + lx) * 64 + kk * 32 + quad * 8];
                accO[d] = __builtin_amdgcn_mfma_f32_16x16x32_bf16(ap, bv, accO[d], 0, 0, 0);
            }
        }
    }

#pragma unroll
    for (int r = 0; r < 4; ++r) {
        const float inv = 1.0f / lrow[r];
        const int nseq = qt * 64 + wave * 16 + quad * 4 + r;
        ushort_t* orow = O + ((size_t)(b * SEQ + nseq)) * EMB + h * HDIM;
#pragma unroll
        for (int d = 0; d < 6; ++d)
            orow[d * 16 + lx] = f2bf(accO[d][r] * inv);
    }
}

// ---------------- projection: Ob bf16 [8192][768] @ Wt2^T + bias -> f32 out ----------------
// 128x128 tiles, grid (64, 6). Wt2: bf16 [768][768] N-major (k contiguous).
__global__ __launch_bounds__(256, 2) void proj_gemm(
        const ushort_t* __restrict__ A, const ushort_t* __restrict__ Wt2,
        const void* __restrict__ bias, float* __restrict__ out,
        const int* __restrict__ flag)
{
    constexpr int KDIM = EMB;
    __shared__ __attribute__((aligned(16))) ushort_t lA[128 * 32];
    __shared__ __attribute__((aligned(16))) ushort_t lB[128 * 32];
    const int t = threadIdx.x;
    const int m0 = blockIdx.x * 128, n0 = blockIdx.y * 128;
    const bool isf = (*flag != 0);
    const int lane = t & 63, wave = t >> 6;
    const int wm = (wave & 1) * 64, wn = (wave >> 1) * 64;
    const int lx = lane & 15, quad = lane >> 4;

    fx4 acc[4][4] = {};

    for (int kt = 0; kt < KDIM / 32; ++kt) {
        const int k0 = kt * 32;
        __syncthreads();
#pragma unroll
        for (int it = 0; it < 2; ++it) {
            int idx = it * 256 + t;              // 512 8-elem segs per tile
            int r = idx >> 2, s8 = (idx & 3) * 8;
            uint4 va = *(const uint4_a*)&A  [(size_t)(m0 + r) * KDIM + k0 + s8];
            uint4 vb = *(const uint4_a*)&Wt2[(size_t)(n0 + r) * KDIM + k0 + s8];
            *(uint4_a*)&lA[r * 32 + s8] = va;
            *(uint4_a*)&lB[r * 32 + s8] = vb;
        }
        __syncthreads();

        bf16x8 af[4], bfr[4];
#pragma unroll
        for (int i = 0; i < 4; ++i)
            af[i] = *(const bf16x8_a*)&lA[(wm + i * 16 + lx) * 32 + quad * 8];
#pragma unroll
        for (int j = 0; j < 4; ++j)
            bfr[j] = *(const bf16x8_a*)&lB[(wn + j * 16 + lx) * 32 + quad * 8];
#pragma unroll
        for (int i = 0; i < 4; ++i)
#pragma unroll
            for (int j = 0; j < 4; ++j)
                acc[i][j] = __builtin_amdgcn_mfma_f32_16x16x32_bf16(af[i], bfr[j], acc[i][j], 0, 0, 0);
    }

#pragma unroll
    for (int j = 0; j < 4; ++j) {
        const int c = n0 + wn + j * 16 + lx;
        const float bv = isf ? ((const float*)bias)[c] : bf2f(((const ushort_t*)bias)[c]);
#pragma unroll
        for (int i = 0; i < 4; ++i) {
            const int mr = m0 + wm + i * 16 + quad * 4;
#pragma unroll
            for (int r = 0; r < 4; ++r)
                out[(size_t)(mr + r) * EMB + c] = acc[i][j][r] + bv;   // f32 store
        }
    }
}

// ---------------- launch ----------------
extern "C" void kernel_launch(void* const* d_in, const int* in_sizes, int n_in,
                              void* d_out, int out_size, void* d_ws, size_t ws_size,
                              hipStream_t stream) {
    const void* x     = d_in[0];
    const void* Wqkv  = d_in[1];
    const void* bqkv  = d_in[2];
    const void* Wproj = d_in[3];
    const void* bproj = d_in[4];
    float* out = (float*)d_out;     // output is float32

    char* ws = (char*)d_ws;
    int* flag = (int*)ws;
    size_t off = 1024;
    ushort_t* Ob  = (ushort_t*)(ws + off);  off += (size_t)MROWS * EMB * 2;   // 12.58 MB
    ushort_t* Wt1 = (ushort_t*)(ws + off);  off += (size_t)2304 * EMB * 2;    //  3.54 MB
    ushort_t* Wt2 = (ushort_t*)(ws + off);  off += (size_t)EMB * EMB * 2;     //  1.18 MB
    ushort_t* stage = (ushort_t*)(ws + off);
    const size_t SLOT_BYTES = (size_t)3 * SEQ * HDIM * 2;   // 1.18 MB per (b,h) unit
    size_t avail = ws_size > off ? ws_size - off : 0;
    int G = (int)(avail / SLOT_BYTES);
    if (G < 1) G = 1;
    if (G > 32) G = 32;

    detect_f32<<<1, 256, 0, stream>>>((const uint32_t*)x, flag);
    transpose_conv<<<dim3(2304 / 64, EMB / 64), 256, 0, stream>>>(Wqkv, Wt1, EMB, 2304, flag);
    transpose_conv<<<dim3(EMB / 64, EMB / 64), 256, 0, stream>>>(Wproj, Wt2, EMB, EMB, flag);
    for (int u0 = 0; u0 < 32; u0 += G) {
        const int gc = (32 - u0 < G) ? (32 - u0) : G;
        qkv_mfma<<<dim3(16, 3, gc), 256, 0, stream>>>(x, Wt1, bqkv, stage, u0, flag);
        attn_flash<<<dim3(SEQ / 64, gc), 256, 0, stream>>>(stage, Ob, u0);
    }
    proj_gemm<<<dim3(MROWS / 128, EMB / 128), 256, 0, stream>>>(Ob, Wt2, bproj, out, flag);
}

// Round 10
// 315.699 us; speedup vs baseline: 3.5149x; 1.3350x over previous
//
#include <hip/hip_runtime.h>
#include <hip/hip_bf16.h>
#include <stdint.h>

#define EMB   768
#define HEADS 8
#define HDIM  96
#define SEQ   2048
#define BATCH 4
#define MROWS (BATCH*SEQ)     // 8192

typedef unsigned short ushort_t;
typedef __bf16 bf16x8 __attribute__((ext_vector_type(8)));
typedef float  fx4    __attribute__((ext_vector_type(4)));
typedef uint4  uint4_a  __attribute__((may_alias));
typedef uint2  uint2_a  __attribute__((may_alias));
typedef bf16x8 bf16x8_a __attribute__((may_alias));

__device__ __forceinline__ float bf2f(ushort_t u) {
    uint32_t v = ((uint32_t)u) << 16;
    return __builtin_bit_cast(float, v);
}
__device__ __forceinline__ ushort_t f2bf(float f) {
    uint32_t u = __builtin_bit_cast(uint32_t, f);
    u += 0x7fffu + ((u >> 16) & 1u);   // RNE
    return (ushort_t)(u >> 16);
}
// packed f32x2 -> bf16x2 (v_cvt_pk_bf16_f32); memcpy because __hip_bfloat162
// is not trivially copyable (bit_cast rejected by clang on ROCm 7.x)
__device__ __forceinline__ uint32_t pk2(float a, float b) {
    __hip_bfloat162 h = __float22bfloat162_rn(make_float2(a, b));
    uint32_t r;
    __builtin_memcpy(&r, &h, 4);
    return r;
}
// async global->LDS, 16B/lane; LDS dest must be wave-uniform base + lane*16
__device__ __forceinline__ void load_lds16(const void* g, void* l) {
    __builtin_amdgcn_global_load_lds(
        (const __attribute__((address_space(1))) uint32_t*)g,
        (__attribute__((address_space(3))) uint32_t*)l, 16, 0, 0);
}

// flag=1 -> input words are f32; flag=0 -> packed bf16 (kept for robustness)
__global__ __launch_bounds__(256) void detect_f32(const uint32_t* __restrict__ x,
                                                  int* __restrict__ flag) {
    __shared__ int cnt;
    if (threadIdx.x == 0) cnt = 0;
    __syncthreads();
    int local = 0;
    for (int i = threadIdx.x; i < 4096; i += 256) {
        uint32_t e = (x[i] >> 7) & 0xFFu;
        local += (e >= 64u && e <= 143u) ? 1 : 0;
    }
    atomicAdd(&cnt, local);
    __syncthreads();
    if (threadIdx.x == 0) *flag = (cnt < 3500) ? 1 : 0;
}

// ---------------- weight transpose (+f32->bf16): src[R][C] -> dst[C][R] bf16 ----------------
__global__ __launch_bounds__(256) void transpose_conv(
        const void* __restrict__ vsrc, ushort_t* __restrict__ dst,
        int R, int C, const int* __restrict__ flag)
{
    __shared__ __attribute__((aligned(16))) ushort_t tile[64][72];  // +8 pad
    const int c0 = blockIdx.x * 64, r0 = blockIdx.y * 64;
    const int t = threadIdx.x;
    const int isf32 = *flag;
#pragma unroll
    for (int i = 0; i < 2; ++i) {
        int idx = i * 256 + t;           // 512 x 8-elem segments
        int r = idx >> 3, c8 = (idx & 7) * 8;
        if (isf32) {
            const float* s = (const float*)vsrc + (size_t)(r0 + r) * C + c0 + c8;
            float4 v0 = *(const float4*)s, v1 = *(const float4*)(s + 4);
            uint32_t tmp[4] = { pk2(v0.x, v0.y), pk2(v0.z, v0.w),
                                pk2(v1.x, v1.y), pk2(v1.z, v1.w) };
            *(uint4_a*)&tile[r][c8] = *(const uint4_a*)tmp;
        } else {
            const ushort_t* s = (const ushort_t*)vsrc + (size_t)(r0 + r) * C + c0 + c8;
            *(uint4_a*)&tile[r][c8] = *(const uint4_a*)s;
        }
    }
    __syncthreads();
#pragma unroll
    for (int i = 0; i < 2; ++i) {
        int idx = i * 256 + t;
        int r = idx >> 3, k8 = (idx & 7) * 8;
        ushort_t tmp[8];
#pragma unroll
        for (int j = 0; j < 8; ++j) tmp[j] = tile[k8 + j][r];
        *(uint4_a*)&dst[(size_t)(c0 + r) * R + r0 + k8] = *(const uint4_a*)tmp;
    }
}

// ---------------- QKV GEMM for one (b,h) unit slice ----------------
// grid (16, 3, gc). Unit u=u0+z: b=u>>3, h=u&7. x[b rows] @ Wqkv[:, h*288..+288)
// Q is pre-scaled by 1/sqrt(768) here. -> stage[g]: Q[2048][96],K[2048][96],Vt[96][2048]
__global__ __launch_bounds__(256, 2) void qkv_mfma(
        const void* __restrict__ x, const ushort_t* __restrict__ Wt1,
        const void* __restrict__ bias,
        ushort_t* __restrict__ stage, int u0, const int* __restrict__ flag)
{
    __shared__ __attribute__((aligned(16))) ushort_t lA[128 * 32];
    __shared__ __attribute__((aligned(16))) ushort_t lB[96 * 32];
    const int g = blockIdx.z, u = u0 + g;
    const int b = u >> 3, h = u & 7;
    const int m0 = blockIdx.x * 128;
    const int n0 = blockIdx.y * 96;           // col within head slice [0,288)
    const bool isf = (*flag != 0);
    const int t = threadIdx.x, lane = t & 63, wave = t >> 6;
    const int lx = lane & 15, quad = lane >> 4;
    const int wm = (wave & 1) * 64, wn = (wave >> 1) * 48;
    const int hb = h * 288;
    const size_t xrow0 = (size_t)(b * SEQ + m0) * EMB;
    const float qscale = 0.03608439182435161f;   // 1/sqrt(768)

    ushort_t* Qg = stage + (size_t)g * (3 * SEQ * HDIM);
    ushort_t* Kg = Qg + SEQ * HDIM;
    ushort_t* Vg = Qg + 2 * SEQ * HDIM;

    fx4 acc[4][3] = {};

    for (int kt = 0; kt < EMB / 32; ++kt) {
        const int k0 = kt * 32;
        __syncthreads();
        if (isf) {
            const float* xf = (const float*)x;
#pragma unroll
            for (int it = 0; it < 4; ++it) {
                int idx = it * 256 + t;              // 1024 float4 segs
                int r = idx >> 3, k4 = (idx & 7) * 4;
                float4 v = *(const float4*)&xf[xrow0 + (size_t)r * EMB + k0 + k4];
                uint32_t tmp[2] = { pk2(v.x, v.y), pk2(v.z, v.w) };
                *(uint2_a*)&lA[r * 32 + k4] = *(const uint2_a*)tmp;
            }
        } else {
            const ushort_t* xb = (const ushort_t*)x;
#pragma unroll
            for (int it = 0; it < 2; ++it) {
                int idx = it * 256 + t;
                int r = idx >> 2, k8 = (idx & 3) * 8;
                *(uint4_a*)&lA[r * 32 + k8] = *(const uint4_a*)&xb[xrow0 + (size_t)r * EMB + k0 + k8];
            }
        }
        // B tile via global->LDS DMA: 384 segs (96 rows x 4); seg t and (t<128) seg 256+t
        {
            int c = t >> 2, s8 = (t & 3) * 8;
            load_lds16(&Wt1[(size_t)(hb + n0 + c) * EMB + k0 + s8], &lB[t * 8]);
            if (t < 128) {
                int idx = 256 + t;
                int c2 = idx >> 2, s82 = (idx & 3) * 8;
                load_lds16(&Wt1[(size_t)(hb + n0 + c2) * EMB + k0 + s82], &lB[idx * 8]);
            }
        }
        __syncthreads();

        bf16x8 af[4], bfr[3];
#pragma unroll
        for (int i = 0; i < 4; ++i)
            af[i] = *(const bf16x8_a*)&lA[(wm + i * 16 + lx) * 32 + quad * 8];
#pragma unroll
        for (int j = 0; j < 3; ++j)
            bfr[j] = *(const bf16x8_a*)&lB[(wn + j * 16 + lx) * 32 + quad * 8];
#pragma unroll
        for (int i = 0; i < 4; ++i)
#pragma unroll
            for (int j = 0; j < 3; ++j)
                acc[i][j] = __builtin_amdgcn_mfma_f32_16x16x32_bf16(af[i], bfr[j], acc[i][j], 0, 0, 0);
    }

    // epilogue: C/D col=lane&15, row=quad*4+reg.  c_local = d*3+s
#pragma unroll
    for (int j = 0; j < 3; ++j) {
        const int cl = n0 + wn + j * 16 + lx;        // [0,288)
        const int dd = cl / 3, s = cl - dd * 3;
        const float bv = isf ? ((const float*)bias)[hb + cl]
                             : bf2f(((const ushort_t*)bias)[hb + cl]);
#pragma unroll
        for (int i = 0; i < 4; ++i) {
            const int ml = m0 + wm + i * 16 + quad * 4;
#pragma unroll
            for (int r = 0; r < 4; ++r) {
                const int nseq = ml + r;
                const float v = acc[i][j][r] + bv;
                if (s == 0)      Qg[(size_t)nseq * HDIM + dd] = f2bf(v * qscale);
                else if (s == 1) Kg[(size_t)nseq * HDIM + dd] = f2bf(v);
                else             Vg[(size_t)dd * SEQ + nseq] = f2bf(v);
            }
        }
    }
}

// ---------------- flash attention (no-max softmax: |s|<=3.5 provably) ----------------
// grid (32 qtiles, gc). O (bf16) -> Ob[b][n][h*96+d]
__global__ __launch_bounds__(256, 2) void attn_flash(
        const ushort_t* __restrict__ stage, ushort_t* __restrict__ O, int u0)
{
    __shared__ __attribute__((aligned(16))) ushort_t lQ[64 * 104];   // +8 pad
    __shared__ __attribute__((aligned(16))) ushort_t lK[64 * 104];
    __shared__ __attribute__((aligned(16))) ushort_t lV[96 * 72];    // +8 pad
    __shared__ __attribute__((aligned(16))) ushort_t lP[4][16 * 72]; // +8 pad, wave-private
    const int t = threadIdx.x, lane = t & 63, wave = t >> 6;
    const int lx = lane & 15, quad = lane >> 4;
    const int qt = blockIdx.x, g = blockIdx.y, u = u0 + g;
    const int b = u >> 3, h = u & 7;
    const ushort_t* Qb = stage + (size_t)g * (3 * SEQ * HDIM);
    const ushort_t* Kb = Qb + SEQ * HDIM;
    const ushort_t* Vb = Qb + 2 * SEQ * HDIM;

#pragma unroll
    for (int it = 0; it < 3; ++it) {
        int idx = it * 256 + t;               // 768 8-elem segs
        int r = idx / 12, s8 = (idx % 12) * 8;
        *(uint4_a*)&lQ[r * 104 + s8] = *(const uint4_a*)&Qb[(size_t)(qt * 64 + r) * HDIM + s8];
    }

    fx4 accO[6] = {};
    float lsum[4] = {0.f, 0.f, 0.f, 0.f};

    for (int kt = 0; kt < SEQ / 64; ++kt) {
        __syncthreads();   // prev-iter lK/lV reads done; makes lQ visible on iter 0
#pragma unroll
        for (int it = 0; it < 3; ++it) {
            int idx = it * 256 + t;
            { int r = idx / 12, s8 = (idx % 12) * 8;
              *(uint4_a*)&lK[r * 104 + s8] = *(const uint4_a*)&Kb[(size_t)(kt * 64 + r) * HDIM + s8]; }
            { int r = idx >> 3, s8 = (idx & 7) * 8;
              *(uint4_a*)&lV[r * 72 + s8] = *(const uint4_a*)&Vb[(size_t)r * SEQ + kt * 64 + s8]; }
        }
        __syncthreads();

        // S = Qs * K^T (Q pre-scaled); wave: 16 q-rows x 64 keys
        fx4 accS[4] = {};
#pragma unroll
        for (int kd = 0; kd < 3; ++kd) {
            bf16x8 aq = *(const bf16x8_a*)&lQ[(wave * 16 + lx) * 104 + kd * 32 + quad * 8];
#pragma unroll
            for (int j = 0; j < 4; ++j) {
                bf16x8 bk = *(const bf16x8_a*)&lK[(j * 16 + lx) * 104 + kd * 32 + quad * 8];
                accS[j] = __builtin_amdgcn_mfma_f32_16x16x32_bf16(aq, bk, accS[j], 0, 0, 0);
            }
        }

        // softmax numerator only: p = exp(s); per-lane partial row-sums
#pragma unroll
        for (int r = 0; r < 4; ++r) {
#pragma unroll
            for (int j = 0; j < 4; ++j) {
                float p = __expf(accS[j][r]);
                lsum[r] += p;
                lP[wave][(quad * 4 + r) * 72 + j * 16 + lx] = f2bf(p);
            }
        }
        // lP is wave-private: only need our own ds_writes drained
        asm volatile("s_waitcnt lgkmcnt(0)" ::: "memory");

        // O += P * V
#pragma unroll
        for (int kk = 0; kk < 2; ++kk) {
            bf16x8 ap = *(const bf16x8_a*)&lP[wave][lx * 72 + kk * 32 + quad * 8];
#pragma unroll
            for (int d = 0; d < 6; ++d) {
                bf16x8 bv = *(const bf16x8_a*)&lV[(d * 16 + lx) * 72 + kk * 32 + quad * 8];
                accO[d] = __builtin_amdgcn_mfma_f32_16x16x32_bf16(ap, bv, accO[d], 0, 0, 0);
            }
        }
    }

    // reduce row-sums across the 16 lanes of each quad (once, at the end)
#pragma unroll
    for (int r = 0; r < 4; ++r) {
        float s = lsum[r];
#pragma unroll
        for (int off = 1; off < 16; off <<= 1) s += __shfl_xor(s, off, 64);
        const float inv = 1.0f / s;
        const int nseq = qt * 64 + wave * 16 + quad * 4 + r;
        ushort_t* orow = O + ((size_t)(b * SEQ + nseq)) * EMB + h * HDIM;
#pragma unroll
        for (int d = 0; d < 6; ++d)
            orow[d * 16 + lx] = f2bf(accO[d][r] * inv);
    }
}

// ---------------- projection: Ob bf16 [8192][768] @ Wt2^T + bias -> f32 out ----------------
__global__ __launch_bounds__(256, 2) void proj_gemm(
        const ushort_t* __restrict__ A, const ushort_t* __restrict__ Wt2,
        const void* __restrict__ bias, float* __restrict__ out,
        const int* __restrict__ flag)
{
    constexpr int KDIM = EMB;
    __shared__ __attribute__((aligned(16))) ushort_t lA[128 * 32];
    __shared__ __attribute__((aligned(16))) ushort_t lB[128 * 32];
    const int t = threadIdx.x;
    const int m0 = blockIdx.x * 128, n0 = blockIdx.y * 128;
    const bool isf = (*flag != 0);
    const int lane = t & 63, wave = t >> 6;
    const int wm = (wave & 1) * 64, wn = (wave >> 1) * 64;
    const int lx = lane & 15, quad = lane >> 4;

    fx4 acc[4][4] = {};

    for (int kt = 0; kt < KDIM / 32; ++kt) {
        const int k0 = kt * 32;
        __syncthreads();
#pragma unroll
        for (int it = 0; it < 2; ++it) {
            int idx = it * 256 + t;              // 512 8-elem segs per tile
            int r = idx >> 2, s8 = (idx & 3) * 8;
            load_lds16(&A  [(size_t)(m0 + r) * KDIM + k0 + s8], &lA[idx * 8]);
            load_lds16(&Wt2[(size_t)(n0 + r) * KDIM + k0 + s8], &lB[idx * 8]);
        }
        __syncthreads();

        bf16x8 af[4], bfr[4];
#pragma unroll
        for (int i = 0; i < 4; ++i)
            af[i] = *(const bf16x8_a*)&lA[(wm + i * 16 + lx) * 32 + quad * 8];
#pragma unroll
        for (int j = 0; j < 4; ++j)
            bfr[j] = *(const bf16x8_a*)&lB[(wn + j * 16 + lx) * 32 + quad * 8];
#pragma unroll
        for (int i = 0; i < 4; ++i)
#pragma unroll
            for (int j = 0; j < 4; ++j)
                acc[i][j] = __builtin_amdgcn_mfma_f32_16x16x32_bf16(af[i], bfr[j], acc[i][j], 0, 0, 0);
    }

#pragma unroll
    for (int j = 0; j < 4; ++j) {
        const int c = n0 + wn + j * 16 + lx;
        const float bv = isf ? ((const float*)bias)[c] : bf2f(((const ushort_t*)bias)[c]);
#pragma unroll
        for (int i = 0; i < 4; ++i) {
            const int mr = m0 + wm + i * 16 + quad * 4;
#pragma unroll
            for (int r = 0; r < 4; ++r)
                out[(size_t)(mr + r) * EMB + c] = acc[i][j][r] + bv;   // f32 store
        }
    }
}

// ---------------- launch ----------------
extern "C" void kernel_launch(void* const* d_in, const int* in_sizes, int n_in,
                              void* d_out, int out_size, void* d_ws, size_t ws_size,
                              hipStream_t stream) {
    const void* x     = d_in[0];
    const void* Wqkv  = d_in[1];
    const void* bqkv  = d_in[2];
    const void* Wproj = d_in[3];
    const void* bproj = d_in[4];
    float* out = (float*)d_out;     // output is float32

    char* ws = (char*)d_ws;
    int* flag = (int*)ws;
    size_t off = 1024;
    ushort_t* Ob  = (ushort_t*)(ws + off);  off += (size_t)MROWS * EMB * 2;   // 12.58 MB
    ushort_t* Wt1 = (ushort_t*)(ws + off);  off += (size_t)2304 * EMB * 2;    //  3.54 MB
    ushort_t* Wt2 = (ushort_t*)(ws + off);  off += (size_t)EMB * EMB * 2;     //  1.18 MB
    ushort_t* stage = (ushort_t*)(ws + off);
    const size_t SLOT_BYTES = (size_t)3 * SEQ * HDIM * 2;   // 1.18 MB per (b,h) unit
    size_t avail = ws_size > off ? ws_size - off : 0;
    int G = (int)(avail / SLOT_BYTES);
    if (G < 1) G = 1;
    if (G > 32) G = 32;

    detect_f32<<<1, 256, 0, stream>>>((const uint32_t*)x, flag);
    transpose_conv<<<dim3(2304 / 64, EMB / 64), 256, 0, stream>>>(Wqkv, Wt1, EMB, 2304, flag);
    transpose_conv<<<dim3(EMB / 64, EMB / 64), 256, 0, stream>>>(Wproj, Wt2, EMB, EMB, flag);
    for (int u0 = 0; u0 < 32; u0 += G) {
        const int gc = (32 - u0 < G) ? (32 - u0) : G;
        qkv_mfma<<<dim3(16, 3, gc), 256, 0, stream>>>(x, Wt1, bqkv, stage, u0, flag);
        attn_flash<<<dim3(SEQ / 64, gc), 256, 0, stream>>>(stage, Ob, u0);
    }
    proj_gemm<<<dim3(MROWS / 128, EMB / 128), 256, 0, stream>>>(Ob, Wt2, bproj, out, flag);
}

// Round 11
// 260.993 us; speedup vs baseline: 4.2516x; 1.2096x over previous
//
#include <hip/hip_runtime.h>
#include <hip/hip_bf16.h>
#include <stdint.h>

#define EMB   768
#define HEADS 8
#define HDIM  96
#define SEQ   2048
#define BATCH 4
#define MROWS (BATCH*SEQ)     // 8192

typedef unsigned short ushort_t;
typedef __bf16 bf16x8 __attribute__((ext_vector_type(8)));
typedef float  fx4    __attribute__((ext_vector_type(4)));
typedef uint4  uint4_a  __attribute__((may_alias));
typedef uint2  uint2_a  __attribute__((may_alias));
typedef bf16x8 bf16x8_a __attribute__((may_alias));

__device__ __forceinline__ float bf2f(ushort_t u) {
    uint32_t v = ((uint32_t)u) << 16;
    return __builtin_bit_cast(float, v);
}
__device__ __forceinline__ ushort_t f2bf(float f) {
    uint32_t u = __builtin_bit_cast(uint32_t, f);
    u += 0x7fffu + ((u >> 16) & 1u);   // RNE
    return (ushort_t)(u >> 16);
}
// packed f32x2 -> bf16x2 (v_cvt_pk_bf16_f32); memcpy: __hip_bfloat162 not trivially copyable
__device__ __forceinline__ uint32_t pk2(float a, float b) {
    __hip_bfloat162 h = __float22bfloat162_rn(make_float2(a, b));
    uint32_t r;
    __builtin_memcpy(&r, &h, 4);
    return r;
}
// async global->LDS, 16B/lane; LDS dest must be wave-uniform base + lane*16
__device__ __forceinline__ void load_lds16(const void* g, void* l) {
    __builtin_amdgcn_global_load_lds(
        (const __attribute__((address_space(1))) uint32_t*)g,
        (__attribute__((address_space(3))) uint32_t*)l, 16, 0, 0);
}

// flag=1 -> input words are f32; flag=0 -> packed bf16
__global__ __launch_bounds__(256) void detect_f32(const uint32_t* __restrict__ x,
                                                  int* __restrict__ flag) {
    __shared__ int cnt;
    if (threadIdx.x == 0) cnt = 0;
    __syncthreads();
    int local = 0;
    for (int i = threadIdx.x; i < 4096; i += 256) {
        uint32_t e = (x[i] >> 7) & 0xFFu;
        local += (e >= 64u && e <= 143u) ? 1 : 0;
    }
    atomicAdd(&cnt, local);
    __syncthreads();
    if (threadIdx.x == 0) *flag = (cnt < 3500) ? 1 : 0;
}

// ---------------- canonicalize x to bf16 (8 elems/thread) ----------------
__global__ __launch_bounds__(256) void canon_x(const void* __restrict__ src,
        ushort_t* __restrict__ dst, const int* __restrict__ flag) {
    const int i = (blockIdx.x * 256 + threadIdx.x) * 8;
    if (*flag) {
        const float* s = (const float*)src + i;
        float4 a = *(const float4*)s, b = *(const float4*)(s + 4);
        uint32_t tmp[4] = { pk2(a.x, a.y), pk2(a.z, a.w), pk2(b.x, b.y), pk2(b.z, b.w) };
        *(uint4_a*)&dst[i] = *(const uint4_a*)tmp;
    } else {
        *(uint4_a*)&dst[i] = *(const uint4_a*)((const ushort_t*)src + i);
    }
}

// ---------------- weight transpose (+f32->bf16): src[R][C] -> dst[C][R] bf16 ----------------
__global__ __launch_bounds__(256) void transpose_conv(
        const void* __restrict__ vsrc, ushort_t* __restrict__ dst,
        int R, int C, const int* __restrict__ flag)
{
    __shared__ __attribute__((aligned(16))) ushort_t tile[64][72];
    const int c0 = blockIdx.x * 64, r0 = blockIdx.y * 64;
    const int t = threadIdx.x;
    const int isf32 = *flag;
#pragma unroll
    for (int i = 0; i < 2; ++i) {
        int idx = i * 256 + t;
        int r = idx >> 3, c8 = (idx & 7) * 8;
        if (isf32) {
            const float* s = (const float*)vsrc + (size_t)(r0 + r) * C + c0 + c8;
            float4 v0 = *(const float4*)s, v1 = *(const float4*)(s + 4);
            uint32_t tmp[4] = { pk2(v0.x, v0.y), pk2(v0.z, v0.w),
                                pk2(v1.x, v1.y), pk2(v1.z, v1.w) };
            *(uint4_a*)&tile[r][c8] = *(const uint4_a*)tmp;
        } else {
            const ushort_t* s = (const ushort_t*)vsrc + (size_t)(r0 + r) * C + c0 + c8;
            *(uint4_a*)&tile[r][c8] = *(const uint4_a*)s;
        }
    }
    __syncthreads();
#pragma unroll
    for (int i = 0; i < 2; ++i) {
        int idx = i * 256 + t;
        int r = idx >> 3, k8 = (idx & 7) * 8;
        ushort_t tmp[8];
#pragma unroll
        for (int j = 0; j < 8; ++j) tmp[j] = tile[k8 + j][r];
        *(uint4_a*)&dst[(size_t)(c0 + r) * R + r0 + k8] = *(const uint4_a*)tmp;
    }
}

// ---------------- QKV GEMM for one (b,h) unit slice ----------------
// grid (16, 3, gc). Xc: bf16 [8192][768]. Q pre-scaled by 1/sqrt(768).
__global__ __launch_bounds__(256, 2) void qkv_mfma(
        const ushort_t* __restrict__ Xc, const ushort_t* __restrict__ Wt1,
        const void* __restrict__ bias,
        ushort_t* __restrict__ stage, int u0, const int* __restrict__ flag)
{
    __shared__ __attribute__((aligned(16))) ushort_t lA[128 * 32];
    __shared__ __attribute__((aligned(16))) ushort_t lB[96 * 32];
    const int g = blockIdx.z, u = u0 + g;
    const int b = u >> 3, h = u & 7;
    const int m0 = blockIdx.x * 128;
    const int n0 = blockIdx.y * 96;
    const bool isf = (*flag != 0);
    const int t = threadIdx.x, lane = t & 63, wave = t >> 6;
    const int lx = lane & 15, quad = lane >> 4;
    const int wm = (wave & 1) * 64, wn = (wave >> 1) * 48;
    const int hb = h * 288;
    const size_t xrow0 = (size_t)(b * SEQ + m0) * EMB;
    const float qscale = 0.03608439182435161f;   // 1/sqrt(768)

    ushort_t* Qg = stage + (size_t)g * (3 * SEQ * HDIM);
    ushort_t* Kg = Qg + SEQ * HDIM;
    ushort_t* Vg = Qg + 2 * SEQ * HDIM;

    fx4 acc[4][3] = {};

    for (int kt = 0; kt < EMB / 32; ++kt) {
        const int k0 = kt * 32;
        __syncthreads();
        // A tile via DMA: 512 segs (128 rows x 4)
#pragma unroll
        for (int it = 0; it < 2; ++it) {
            int idx = it * 256 + t;
            int r = idx >> 2, k8 = (idx & 3) * 8;
            load_lds16(&Xc[xrow0 + (size_t)r * EMB + k0 + k8], &lA[idx * 8]);
        }
        // B tile via DMA: 384 segs (96 rows x 4)
        {
            int c = t >> 2, s8 = (t & 3) * 8;
            load_lds16(&Wt1[(size_t)(hb + n0 + c) * EMB + k0 + s8], &lB[t * 8]);
            if (t < 128) {
                int idx = 256 + t;
                int c2 = idx >> 2, s82 = (idx & 3) * 8;
                load_lds16(&Wt1[(size_t)(hb + n0 + c2) * EMB + k0 + s82], &lB[idx * 8]);
            }
        }
        __syncthreads();

        bf16x8 af[4], bfr[3];
#pragma unroll
        for (int i = 0; i < 4; ++i)
            af[i] = *(const bf16x8_a*)&lA[(wm + i * 16 + lx) * 32 + quad * 8];
#pragma unroll
        for (int j = 0; j < 3; ++j)
            bfr[j] = *(const bf16x8_a*)&lB[(wn + j * 16 + lx) * 32 + quad * 8];
#pragma unroll
        for (int i = 0; i < 4; ++i)
#pragma unroll
            for (int j = 0; j < 3; ++j)
                acc[i][j] = __builtin_amdgcn_mfma_f32_16x16x32_bf16(af[i], bfr[j], acc[i][j], 0, 0, 0);
    }

    // epilogue: C/D col=lane&15, row=quad*4+reg.  c_local = d*3+s
#pragma unroll
    for (int j = 0; j < 3; ++j) {
        const int cl = n0 + wn + j * 16 + lx;
        const int dd = cl / 3, s = cl - dd * 3;
        const float bv = isf ? ((const float*)bias)[hb + cl]
                             : bf2f(((const ushort_t*)bias)[hb + cl]);
#pragma unroll
        for (int i = 0; i < 4; ++i) {
            const int ml = m0 + wm + i * 16 + quad * 4;
#pragma unroll
            for (int r = 0; r < 4; ++r) {
                const int nseq = ml + r;
                const float v = acc[i][j][r] + bv;
                if (s == 0)      Qg[(size_t)nseq * HDIM + dd] = f2bf(v * qscale);
                else if (s == 1) Kg[(size_t)nseq * HDIM + dd] = f2bf(v);
                else             Vg[(size_t)dd * SEQ + nseq] = f2bf(v);
            }
        }
    }
}

// ---------------- flash attention v2: 128 q-rows/block, 32 q-rows/wave ----------------
// grid (SEQ/128=16, gc). LDS 62.98 KB -> 2 blocks/CU. No-max softmax (|s|<=3.5).
__global__ __launch_bounds__(256, 2) void attn_flash(
        const ushort_t* __restrict__ stage, ushort_t* __restrict__ O, int u0)
{
    __shared__ __attribute__((aligned(16))) ushort_t lQ[128 * 104];  // 26.0 KB
    __shared__ __attribute__((aligned(16))) ushort_t lK[64 * 104];   // 13.0 KB
    __shared__ __attribute__((aligned(16))) ushort_t lV[96 * 72];    // 13.5 KB
    __shared__ __attribute__((aligned(16))) ushort_t lP[4][16 * 72]; //  9.0 KB wave-private
    const int t = threadIdx.x, lane = t & 63, wave = t >> 6;
    const int lx = lane & 15, quad = lane >> 4;
    const int qt = blockIdx.x, g = blockIdx.y, u = u0 + g;
    const int b = u >> 3, h = u & 7;
    const ushort_t* Qb = stage + (size_t)g * (3 * SEQ * HDIM);
    const ushort_t* Kb = Qb + SEQ * HDIM;
    const ushort_t* Vb = Qb + 2 * SEQ * HDIM;

    // stage Q: 128 x 96 = 1536 8-elem segs
#pragma unroll
    for (int it = 0; it < 6; ++it) {
        int idx = it * 256 + t;
        int r = idx / 12, s8 = (idx % 12) * 8;
        *(uint4_a*)&lQ[r * 104 + s8] = *(const uint4_a*)&Qb[(size_t)(qt * 128 + r) * HDIM + s8];
    }

    fx4 accO[2][6] = {};
    float lsum[2][4] = {};

    for (int kt = 0; kt < SEQ / 64; ++kt) {
        __syncthreads();
#pragma unroll
        for (int it = 0; it < 3; ++it) {
            int idx = it * 256 + t;
            { int r = idx / 12, s8 = (idx % 12) * 8;
              *(uint4_a*)&lK[r * 104 + s8] = *(const uint4_a*)&Kb[(size_t)(kt * 64 + r) * HDIM + s8]; }
            { int r = idx >> 3, s8 = (idx & 7) * 8;
              *(uint4_a*)&lV[r * 72 + s8] = *(const uint4_a*)&Vb[(size_t)r * SEQ + kt * 64 + s8]; }
        }
        __syncthreads();

        // S = Qs*K^T : wave covers 32 q-rows (2 m-frags) x 64 keys
        fx4 accS[2][4] = {};
#pragma unroll
        for (int kd = 0; kd < 3; ++kd) {
            bf16x8 aq0 = *(const bf16x8_a*)&lQ[(wave * 32 + lx) * 104 + kd * 32 + quad * 8];
            bf16x8 aq1 = *(const bf16x8_a*)&lQ[(wave * 32 + 16 + lx) * 104 + kd * 32 + quad * 8];
#pragma unroll
            for (int j = 0; j < 4; ++j) {
                bf16x8 bk = *(const bf16x8_a*)&lK[(j * 16 + lx) * 104 + kd * 32 + quad * 8];
                accS[0][j] = __builtin_amdgcn_mfma_f32_16x16x32_bf16(aq0, bk, accS[0][j], 0, 0, 0);
                accS[1][j] = __builtin_amdgcn_mfma_f32_16x16x32_bf16(aq1, bk, accS[1][j], 0, 0, 0);
            }
        }

        // preload V fragments once (shared across both m half-passes)
        bf16x8 bv[2][6];
#pragma unroll
        for (int kk = 0; kk < 2; ++kk)
#pragma unroll
            for (int d = 0; d < 6; ++d)
                bv[kk][d] = *(const bf16x8_a*)&lV[(d * 16 + lx) * 72 + kk * 32 + quad * 8];

        // two half-passes over m-frags, reusing lP[wave]
#pragma unroll
        for (int i = 0; i < 2; ++i) {
#pragma unroll
            for (int r = 0; r < 4; ++r) {
#pragma unroll
                for (int j = 0; j < 4; ++j) {
                    float p = __expf(accS[i][j][r]);
                    lsum[i][r] += p;
                    lP[wave][(quad * 4 + r) * 72 + j * 16 + lx] = f2bf(p);
                }
            }
            asm volatile("s_waitcnt lgkmcnt(0)" ::: "memory");  // wave-private lP drained
#pragma unroll
            for (int kk = 0; kk < 2; ++kk) {
                bf16x8 ap = *(const bf16x8_a*)&lP[wave][lx * 72 + kk * 32 + quad * 8];
#pragma unroll
                for (int d = 0; d < 6; ++d)
                    accO[i][d] = __builtin_amdgcn_mfma_f32_16x16x32_bf16(ap, bv[kk][d], accO[i][d], 0, 0, 0);
            }
        }
    }

    // epilogue
#pragma unroll
    for (int i = 0; i < 2; ++i) {
#pragma unroll
        for (int r = 0; r < 4; ++r) {
            float s = lsum[i][r];
#pragma unroll
            for (int off = 1; off < 16; off <<= 1) s += __shfl_xor(s, off, 64);
            const float inv = 1.0f / s;
            const int nseq = qt * 128 + wave * 32 + i * 16 + quad * 4 + r;
            ushort_t* orow = O + ((size_t)(b * SEQ + nseq)) * EMB + h * HDIM;
#pragma unroll
            for (int d = 0; d < 6; ++d)
                orow[d * 16 + lx] = f2bf(accO[i][d][r] * inv);
        }
    }
}

// ---------------- projection: Ob bf16 [8192][768] @ Wt2^T + bias -> f32 out ----------------
__global__ __launch_bounds__(256, 2) void proj_gemm(
        const ushort_t* __restrict__ A, const ushort_t* __restrict__ Wt2,
        const void* __restrict__ bias, float* __restrict__ out,
        const int* __restrict__ flag)
{
    constexpr int KDIM = EMB;
    __shared__ __attribute__((aligned(16))) ushort_t lA[128 * 32];
    __shared__ __attribute__((aligned(16))) ushort_t lB[128 * 32];
    const int t = threadIdx.x;
    const int m0 = blockIdx.x * 128, n0 = blockIdx.y * 128;
    const bool isf = (*flag != 0);
    const int lane = t & 63, wave = t >> 6;
    const int wm = (wave & 1) * 64, wn = (wave >> 1) * 64;
    const int lx = lane & 15, quad = lane >> 4;

    fx4 acc[4][4] = {};

    for (int kt = 0; kt < KDIM / 32; ++kt) {
        const int k0 = kt * 32;
        __syncthreads();
#pragma unroll
        for (int it = 0; it < 2; ++it) {
            int idx = it * 256 + t;
            int r = idx >> 2, s8 = (idx & 3) * 8;
            load_lds16(&A  [(size_t)(m0 + r) * KDIM + k0 + s8], &lA[idx * 8]);
            load_lds16(&Wt2[(size_t)(n0 + r) * KDIM + k0 + s8], &lB[idx * 8]);
        }
        __syncthreads();

        bf16x8 af[4], bfr[4];
#pragma unroll
        for (int i = 0; i < 4; ++i)
            af[i] = *(const bf16x8_a*)&lA[(wm + i * 16 + lx) * 32 + quad * 8];
#pragma unroll
        for (int j = 0; j < 4; ++j)
            bfr[j] = *(const bf16x8_a*)&lB[(wn + j * 16 + lx) * 32 + quad * 8];
#pragma unroll
        for (int i = 0; i < 4; ++i)
#pragma unroll
            for (int j = 0; j < 4; ++j)
                acc[i][j] = __builtin_amdgcn_mfma_f32_16x16x32_bf16(af[i], bfr[j], acc[i][j], 0, 0, 0);
    }

#pragma unroll
    for (int j = 0; j < 4; ++j) {
        const int c = n0 + wn + j * 16 + lx;
        const float bv = isf ? ((const float*)bias)[c] : bf2f(((const ushort_t*)bias)[c]);
#pragma unroll
        for (int i = 0; i < 4; ++i) {
            const int mr = m0 + wm + i * 16 + quad * 4;
#pragma unroll
            for (int r = 0; r < 4; ++r)
                out[(size_t)(mr + r) * EMB + c] = acc[i][j][r] + bv;   // f32 store
        }
    }
}

// ---------------- launch ----------------
extern "C" void kernel_launch(void* const* d_in, const int* in_sizes, int n_in,
                              void* d_out, int out_size, void* d_ws, size_t ws_size,
                              hipStream_t stream) {
    const void* x     = d_in[0];
    const void* Wqkv  = d_in[1];
    const void* bqkv  = d_in[2];
    const void* Wproj = d_in[3];
    const void* bproj = d_in[4];
    float* out = (float*)d_out;     // output is float32

    char* ws = (char*)d_ws;
    int* flag = (int*)ws;
    size_t off = 1024;
    ushort_t* Ob  = (ushort_t*)(ws + off);  off += (size_t)MROWS * EMB * 2;   // 12.58 MB
    ushort_t* Xc  = (ushort_t*)(ws + off);  off += (size_t)MROWS * EMB * 2;   // 12.58 MB
    ushort_t* Wt1 = (ushort_t*)(ws + off);  off += (size_t)2304 * EMB * 2;    //  3.54 MB
    ushort_t* Wt2 = (ushort_t*)(ws + off);  off += (size_t)EMB * EMB * 2;     //  1.18 MB
    ushort_t* stage = (ushort_t*)(ws + off);
    const size_t SLOT_BYTES = (size_t)3 * SEQ * HDIM * 2;   // 1.18 MB per (b,h) unit
    size_t avail = ws_size > off ? ws_size - off : 0;
    int G = (int)(avail / SLOT_BYTES);
    if (G < 1) G = 1;
    if (G > 32) G = 32;

    detect_f32<<<1, 256, 0, stream>>>((const uint32_t*)x, flag);
    canon_x<<<dim3(MROWS * EMB / (256 * 8)), 256, 0, stream>>>(x, Xc, flag);
    transpose_conv<<<dim3(2304 / 64, EMB / 64), 256, 0, stream>>>(Wqkv, Wt1, EMB, 2304, flag);
    transpose_conv<<<dim3(EMB / 64, EMB / 64), 256, 0, stream>>>(Wproj, Wt2, EMB, EMB, flag);
    for (int u0 = 0; u0 < 32; u0 += G) {
        const int gc = (32 - u0 < G) ? (32 - u0) : G;
        qkv_mfma<<<dim3(16, 3, gc), 256, 0, stream>>>(Xc, Wt1, bqkv, stage, u0, flag);
        attn_flash<<<dim3(SEQ / 128, gc), 256, 0, stream>>>(stage, Ob, u0);
    }
    proj_gemm<<<dim3(MROWS / 128, EMB / 128), 256, 0, stream>>>(Ob, Wt2, bproj, out, flag);
}